// Round 4
// baseline (389.768 us; speedup 1.0000x reference)
//
#include <hip/hip_runtime.h>
#include <hip/hip_bf16.h>

typedef __attribute__((ext_vector_type(8))) short bf16x8;
typedef __attribute__((ext_vector_type(4))) float f32x4;
typedef __attribute__((ext_vector_type(8))) unsigned short u16x8;

__device__ __forceinline__ unsigned short f2bf(float f) {
  union { float f; unsigned u; } v; v.f = f;
  unsigned r = v.u + 0x7FFFu + ((v.u >> 16) & 1u);
  return (unsigned short)(r >> 16);
}

__device__ __forceinline__ bf16x8 cvt8(f32x4 a, f32x4 b) {
  u16x8 o;
  o[0] = f2bf(a[0]); o[1] = f2bf(a[1]); o[2] = f2bf(a[2]); o[3] = f2bf(a[3]);
  o[4] = f2bf(b[0]); o[5] = f2bf(b[1]); o[6] = f2bf(b[2]); o[7] = f2bf(b[3]);
  union { u16x8 u; bf16x8 s; } c; c.u = o;
  return c.s;
}

// ---------------------------------------------------------------------------
// 128x128-tile NT GEMM with FUSED fp32->bf16 input conversion (proven r3).
__global__ __launch_bounds__(256, 2)
void gemm128_f32in(const float* __restrict__ A, const float* __restrict__ B,
                   unsigned short* __restrict__ Cb,
                   const float* __restrict__ bias, const float* __restrict__ scale,
                   int M, int N, int K) {
  __shared__ unsigned short As[128 * 64];
  __shared__ unsigned short Bs[128 * 64];

  int nby = N >> 7;
  int nwg = gridDim.x;
  int wg = blockIdx.x;
  if ((nwg & 7) == 0) {
    int cpx = nwg >> 3;
    wg = (wg & 7) * cpx + (wg >> 3);
  }
  int bm = wg / nby, bn = wg % nby;
  int m0 = bm << 7, n0 = bn << 7;

  int tid = threadIdx.x;
  int w = tid >> 6, lane = tid & 63;
  int wave_m = (w >> 1) << 6;
  int wave_n = (w & 1) << 6;

  int srow = tid >> 3, c8 = tid & 7;
  int slot = c8 ^ (srow & 7);
  const float* Ag = A + (size_t)(m0 + srow) * K + c8 * 8;
  const float* Bg = B + (size_t)(n0 + srow) * K + c8 * 8;
  int dst = srow * 64 + slot * 8;

  int hi = lane >> 4, lo = lane & 15, e7 = lane & 7;
  int a_base[2], b_base[2];
#pragma unroll
  for (int kk = 0; kk < 2; ++kk) {
    int sl = ((kk << 2) + hi) ^ e7;
    a_base[kk] = (wave_m + lo) * 64 + sl * 8;
    b_base[kk] = (wave_n + lo) * 64 + sl * 8;
  }

  f32x4 acc[4][4] = {};
  f32x4 ra[4][2], rb[4][2];

#define LOADK(KT)                                                         \
  {                                                                       \
    _Pragma("unroll") for (int i_ = 0; i_ < 4; ++i_) {                    \
      const float* pa = Ag + (size_t)(KT) * 64 + (size_t)(i_ * 32) * K;   \
      const float* pb = Bg + (size_t)(KT) * 64 + (size_t)(i_ * 32) * K;   \
      ra[i_][0] = *(const f32x4*)pa; ra[i_][1] = *(const f32x4*)(pa + 4); \
      rb[i_][0] = *(const f32x4*)pb; rb[i_][1] = *(const f32x4*)(pb + 4); \
    }                                                                     \
  }

  LOADK(0);
  int ksteps = K >> 6;
  for (int kt = 0; kt < ksteps; ++kt) {
#pragma unroll
    for (int i = 0; i < 4; ++i) {
      *(bf16x8*)(&As[dst + i * 2048]) = cvt8(ra[i][0], ra[i][1]);
      *(bf16x8*)(&Bs[dst + i * 2048]) = cvt8(rb[i][0], rb[i][1]);
    }
    __syncthreads();
    if (kt + 1 < ksteps) LOADK(kt + 1);

    bf16x8 afr[4][2], bfr[4][2];
#pragma unroll
    for (int kk = 0; kk < 2; ++kk) {
#pragma unroll
      for (int t2 = 0; t2 < 4; ++t2) {
        afr[t2][kk] = *(const bf16x8*)(&As[a_base[kk] + t2 * 1024]);
        bfr[t2][kk] = *(const bf16x8*)(&Bs[b_base[kk] + t2 * 1024]);
      }
    }
#pragma unroll
    for (int kk = 0; kk < 2; ++kk) {
#pragma unroll
      for (int mt = 0; mt < 4; ++mt) {
#pragma unroll
        for (int nt = 0; nt < 4; ++nt) {
          acc[mt][nt] = __builtin_amdgcn_mfma_f32_16x16x32_bf16(
              afr[mt][kk], bfr[nt][kk], acc[mt][nt], 0, 0, 0);
        }
      }
    }
    __syncthreads();
  }
#undef LOADK

  float bi[4], sc[4];
#pragma unroll
  for (int nt = 0; nt < 4; ++nt) {
    int n = n0 + wave_n + nt * 16 + lo;
    bi[nt] = bias ? bias[n] : 0.f;
    sc[nt] = scale ? scale[n] : 1.f;
  }
#pragma unroll
  for (int mt = 0; mt < 4; ++mt) {
#pragma unroll
    for (int r = 0; r < 4; ++r) {
      size_t m = (size_t)(m0 + wave_m + mt * 16 + hi * 4 + r);
      unsigned short* rowp = Cb + m * (size_t)N + (n0 + wave_n + lo);
#pragma unroll
      for (int nt = 0; nt < 4; ++nt) {
        float v = fmaxf(acc[mt][nt][r] + bi[nt], 0.f) * sc[nt];
        rowp[nt * 16] = f2bf(v);
      }
    }
  }
}

// ---------------------------------------------------------------------------
// PERSISTENT main GEMM: C[4096][32000] = A[4096][512] @ B[32000][512]^T + b.
// BM=128, BN=256, BK=64. 512 thr = 8 waves (2M x 4N), wave tile 64x64.
// LDS 96 KiB: 2buf x (A 128x64 + B 256x64) bf16. acc double-buffered (accA/accB):
// while tile t accumulates into accCUR, tile t-1 streams out from accPREV at
// 4 stores/phase (16 phases/tile) -> continuous HBM write stream, tiny vmcnt
// drains (~8 stores + 6 loads) instead of 256 KB bursts.
// Grid = 250 blocks: grp=bid/125 (m half, 16 tiles of 128 rows), bn=bid%125.
__global__ __launch_bounds__(512, 2)
void gemm_main(const unsigned short* __restrict__ A,
               const unsigned short* __restrict__ B,
               float* __restrict__ Cf,
               const float* __restrict__ bconst) {
  __shared__ unsigned short As[2][128 * 64];
  __shared__ unsigned short Bs[2][256 * 64];

  int bid = blockIdx.x;
  int grp = bid / 125;
  int bn = bid - grp * 125;
  int n0 = bn << 8;

  int tid = threadIdx.x;
  int lane = tid & 63;
  int wid = tid >> 6;
  int wm = wid >> 2, wn = wid & 3;   // 2M x 4N waves
  int lo = lane & 15, hi = lane >> 4;

  int srow = tid >> 3;
  int kc = (tid & 7) ^ (srow & 7);
  const unsigned short* Asrc = A + (size_t)(grp * 2048 + srow) * 512 + kc * 8;
  const unsigned short* Bsrc = B + (size_t)(n0 + srow) * 512 + kc * 8;
  int ldst = tid * 8;

  int soff0 = (hi ^ (lo & 7)) * 8;
  int soff1 = ((4 + hi) ^ (lo & 7)) * 8;
  int sA_row = (wm * 64 + lo) * 64;
  int sB_row = (wn * 64 + lo) * 64;

  float badd = bconst[0];
  float* cbase = Cf + (size_t)(n0 + wn * 64 + lo);

  f32x4 accA[4][4], accB[4][4];
#pragma unroll
  for (int z = 0; z < 4; ++z)
#pragma unroll
    for (int zz = 0; zz < 4; ++zz) {
      accA[z][zz] = (f32x4){0.f, 0.f, 0.f, 0.f};
      accB[z][zz] = (f32x4){0.f, 0.f, 0.f, 0.f};
    }
  bf16x8 afr[4][2], bfr[2][2];

#define STAGE_ALL(BUF, G)                                                      \
  {                                                                            \
    size_t aoff_ = (size_t)((G) >> 3) * 65536 + (size_t)(((G) & 7) * 64);      \
    size_t boff_ = (size_t)(((G) & 7) * 64);                                   \
    _Pragma("unroll") for (int i_ = 0; i_ < 2; ++i_)                           \
      __builtin_amdgcn_global_load_lds(                                        \
          (const __attribute__((address_space(1))) void*)(                     \
              Asrc + aoff_ + (size_t)(i_ * 64) * 512),                         \
          (__attribute__((address_space(3))) void*)(&As[BUF][0] + i_ * 4096 +  \
                                                    ldst),                     \
          16, 0, 0);                                                           \
    _Pragma("unroll") for (int i_ = 0; i_ < 4; ++i_)                           \
      __builtin_amdgcn_global_load_lds(                                        \
          (const __attribute__((address_space(1))) void*)(                     \
              Bsrc + boff_ + (size_t)(i_ * 64) * 512),                         \
          (__attribute__((address_space(3))) void*)(&Bs[BUF][0] + i_ * 4096 +  \
                                                    ldst),                     \
          16, 0, 0);                                                           \
  }

#define ST4(HPL, ACCP, TP, T)                                                  \
  if (HPL) {                                                                   \
    const int mt_ = (TP) >> 2, nt_ = (TP) & 3;                                 \
    float* p_ = cbase +                                                        \
                (size_t)(grp * 2048 + ((T)-1) * 128 + wm * 64 + mt_ * 16 +     \
                         hi * 4) * 32000 + nt_ * 16;                           \
    p_[0]     = ACCP[mt_][nt_][0] + badd;                                      \
    p_[32000] = ACCP[mt_][nt_][1] + badd;                                      \
    p_[64000] = ACCP[mt_][nt_][2] + badd;                                      \
    p_[96000] = ACCP[mt_][nt_][3] + badd;                                      \
  }

#define PHASE(BUF, NP, READA, ACCC, STO, STG, VME)                             \
  {                                                                            \
    STO;                                                                       \
    STG;                                                                       \
    if (READA) {                                                               \
      _Pragma("unroll") for (int mt_ = 0; mt_ < 4; ++mt_) {                    \
        afr[mt_][0] =                                                          \
            *(const bf16x8*)(&As[BUF][sA_row + mt_ * 1024 + soff0]);           \
        afr[mt_][1] =                                                          \
            *(const bf16x8*)(&As[BUF][sA_row + mt_ * 1024 + soff1]);           \
      }                                                                        \
    }                                                                          \
    _Pragma("unroll") for (int j_ = 0; j_ < 2; ++j_) {                         \
      bfr[j_][0] = *(const bf16x8*)(                                           \
          &Bs[BUF][sB_row + ((NP)*2 + j_) * 1024 + soff0]);                    \
      bfr[j_][1] = *(const bf16x8*)(                                           \
          &Bs[BUF][sB_row + ((NP)*2 + j_) * 1024 + soff1]);                    \
    }                                                                          \
    __builtin_amdgcn_s_barrier();                                              \
    asm volatile("s_waitcnt lgkmcnt(0)" ::: "memory");                         \
    __builtin_amdgcn_sched_barrier(0);                                         \
    __builtin_amdgcn_s_setprio(1);                                             \
    _Pragma("unroll") for (int mt_ = 0; mt_ < 4; ++mt_)                        \
      _Pragma("unroll") for (int j_ = 0; j_ < 2; ++j_)                         \
        _Pragma("unroll") for (int kk_ = 0; kk_ < 2; ++kk_)                    \
          ACCC[mt_][(NP)*2 + j_] = __builtin_amdgcn_mfma_f32_16x16x32_bf16(    \
              afr[mt_][kk_], bfr[j_][kk_], ACCC[mt_][(NP)*2 + j_], 0, 0, 0);   \
    __builtin_amdgcn_s_setprio(0);                                             \
    VME;                                                                       \
    __builtin_amdgcn_s_barrier();                                              \
  }

#define ITER(JJ, ACCC, ACCP, HPL, T)                                           \
  {                                                                            \
    int g1_ = (T) * 8 + (JJ) * 2 + 1;                                          \
    int g2_ = g1_ + 1;                                                         \
    PHASE(0, 0, 1, ACCC, ST4(HPL, ACCP, (JJ)*4 + 0, T),                        \
          { STAGE_ALL(1, g1_); }, {})                                          \
    PHASE(0, 1, 0, ACCC, ST4(HPL, ACCP, (JJ)*4 + 1, T), {},                    \
          { asm volatile("s_waitcnt vmcnt(0)" ::: "memory"); })                \
    PHASE(1, 0, 1, ACCC, ST4(HPL, ACCP, (JJ)*4 + 2, T),                        \
          { if (g2_ < 128) STAGE_ALL(0, g2_); }, {})                           \
    PHASE(1, 1, 0, ACCC, ST4(HPL, ACCP, (JJ)*4 + 3, T), {},                    \
          { asm volatile("s_waitcnt vmcnt(0)" ::: "memory"); })                \
  }

#define INNER(ACCC, ACCP, HPL, T)                                              \
  {                                                                            \
    ITER(0, ACCC, ACCP, HPL, T)                                                \
    ITER(1, ACCC, ACCP, HPL, T)                                                \
    ITER(2, ACCC, ACCP, HPL, T)                                                \
    ITER(3, ACCC, ACCP, HPL, T)                                                \
    _Pragma("unroll") for (int z_ = 0; z_ < 4; ++z_)                           \
      _Pragma("unroll") for (int zz_ = 0; zz_ < 4; ++zz_)                      \
        ACCP[z_][zz_] = (f32x4){0.f, 0.f, 0.f, 0.f};                           \
  }

  // prologue: stage global K-step 0 into buf0
  STAGE_ALL(0, 0);
  asm volatile("s_waitcnt vmcnt(0)" ::: "memory");
  __builtin_amdgcn_s_barrier();

  INNER(accA, accB, 0, 0)        // tile 0 -> accA (no prev stores)
  INNER(accB, accA, 1, 1)        // tile 1 -> accB, stream tile 0
  for (int tt = 1; tt < 8; ++tt) {
    INNER(accA, accB, 1, 2 * tt)      // even tile -> accA, stream odd
    INNER(accB, accA, 1, 2 * tt + 1)  // odd tile -> accB, stream even
  }
#undef INNER
#undef ITER
#undef PHASE
#undef ST4
#undef STAGE_ALL

  // final burst: tile 15 from accB (pipeline finished)
  {
    size_t rbase = (size_t)(grp * 2048 + 15 * 128 + wm * 64 + hi * 4);
#pragma unroll
    for (int mt = 0; mt < 4; ++mt)
#pragma unroll
      for (int r = 0; r < 4; ++r) {
        float* rowp = cbase + (rbase + mt * 16 + r) * (size_t)32000;
#pragma unroll
        for (int nt = 0; nt < 4; ++nt)
          rowp[nt * 16] = accB[mt][nt][r] + badd;
      }
  }
}

extern "C" void kernel_launch(void* const* d_in, const int* in_sizes, int n_in,
                              void* d_out, int out_size, void* d_ws, size_t ws_size,
                              hipStream_t stream) {
  const float* h  = (const float*)d_in[0];  // [4096,1024]
  const float* l  = (const float*)d_in[1];  // [32000,512]
  const float* Wh = (const float*)d_in[2];  // [512,1024]
  const float* bh = (const float*)d_in[3];  // [512]
  const float* Wl = (const float*)d_in[4];  // [512,512]
  const float* bl = (const float*)d_in[5];  // [512]
  const float* w  = (const float*)d_in[6];  // [512]
  const float* b  = (const float*)d_in[7];  // [1]
  float* out = (float*)d_out;               // [4096,32000]

  char* ws = (char*)d_ws;
  unsigned short* hawbf = (unsigned short*)(ws + 0);        //  4,194,304 B
  unsigned short* labf  = (unsigned short*)(ws + 4194304);  // 32,768,000 B

  // GEMM1: hawbf = relu(h @ Wh^T + bh) * w   [4096,512], K=1024 (fp32 in)
  gemm128_f32in<<<dim3(32 * 4), dim3(256), 0, stream>>>(
      h, Wh, hawbf, bh, w, 4096, 512, 1024);
  // GEMM2: labf = relu(l @ Wl^T + bl)        [32000,512], K=512 (fp32 in)
  gemm128_f32in<<<dim3(250 * 4), dim3(256), 0, stream>>>(
      l, Wl, labf, bl, nullptr, 32000, 512, 512);
  // main: persistent 8-wave, acc-dbuf, spread-store pipeline
  gemm_main<<<dim3(250), dim3(512), 0, stream>>>(hawbf, labf, out, b);
}

// Round 5
// 291.836 us; speedup vs baseline: 1.3356x; 1.3356x over previous
//
#include <hip/hip_runtime.h>
#include <hip/hip_bf16.h>

typedef __attribute__((ext_vector_type(8))) short bf16x8;
typedef __attribute__((ext_vector_type(4))) float f32x4;
typedef __attribute__((ext_vector_type(8))) unsigned short u16x8;

__device__ __forceinline__ unsigned short f2bf(float f) {
  union { float f; unsigned u; } v; v.f = f;
  unsigned r = v.u + 0x7FFFu + ((v.u >> 16) & 1u);
  return (unsigned short)(r >> 16);
}

__device__ __forceinline__ bf16x8 cvt8(f32x4 a, f32x4 b) {
  u16x8 o;
  o[0] = f2bf(a[0]); o[1] = f2bf(a[1]); o[2] = f2bf(a[2]); o[3] = f2bf(a[3]);
  o[4] = f2bf(b[0]); o[5] = f2bf(b[1]); o[6] = f2bf(b[2]); o[7] = f2bf(b[3]);
  union { u16x8 u; bf16x8 s; } c; c.u = o;
  return c.s;
}

// ---------------------------------------------------------------------------
// 128x128-tile NT GEMM with FUSED fp32->bf16 input conversion (proven r3/r4).
// Outputs (ws intermediates) use NORMAL stores -> stay L2/L3-resident for the
// main GEMM to consume.
__global__ __launch_bounds__(256, 2)
void gemm128_f32in(const float* __restrict__ A, const float* __restrict__ B,
                   unsigned short* __restrict__ Cb,
                   const float* __restrict__ bias, const float* __restrict__ scale,
                   int M, int N, int K) {
  __shared__ unsigned short As[128 * 64];
  __shared__ unsigned short Bs[128 * 64];

  int nby = N >> 7;
  int nwg = gridDim.x;
  int wg = blockIdx.x;
  if ((nwg & 7) == 0) {
    int cpx = nwg >> 3;
    wg = (wg & 7) * cpx + (wg >> 3);
  }
  int bm = wg / nby, bn = wg % nby;
  int m0 = bm << 7, n0 = bn << 7;

  int tid = threadIdx.x;
  int w = tid >> 6, lane = tid & 63;
  int wave_m = (w >> 1) << 6;
  int wave_n = (w & 1) << 6;

  int srow = tid >> 3, c8 = tid & 7;
  int slot = c8 ^ (srow & 7);
  const float* Ag = A + (size_t)(m0 + srow) * K + c8 * 8;
  const float* Bg = B + (size_t)(n0 + srow) * K + c8 * 8;
  int dst = srow * 64 + slot * 8;

  int hi = lane >> 4, lo = lane & 15, e7 = lane & 7;
  int a_base[2], b_base[2];
#pragma unroll
  for (int kk = 0; kk < 2; ++kk) {
    int sl = ((kk << 2) + hi) ^ e7;
    a_base[kk] = (wave_m + lo) * 64 + sl * 8;
    b_base[kk] = (wave_n + lo) * 64 + sl * 8;
  }

  f32x4 acc[4][4] = {};
  f32x4 ra[4][2], rb[4][2];

#define LOADK(KT)                                                         \
  {                                                                       \
    _Pragma("unroll") for (int i_ = 0; i_ < 4; ++i_) {                    \
      const float* pa = Ag + (size_t)(KT) * 64 + (size_t)(i_ * 32) * K;   \
      const float* pb = Bg + (size_t)(KT) * 64 + (size_t)(i_ * 32) * K;   \
      ra[i_][0] = *(const f32x4*)pa; ra[i_][1] = *(const f32x4*)(pa + 4); \
      rb[i_][0] = *(const f32x4*)pb; rb[i_][1] = *(const f32x4*)(pb + 4); \
    }                                                                     \
  }

  LOADK(0);
  int ksteps = K >> 6;
  for (int kt = 0; kt < ksteps; ++kt) {
#pragma unroll
    for (int i = 0; i < 4; ++i) {
      *(bf16x8*)(&As[dst + i * 2048]) = cvt8(ra[i][0], ra[i][1]);
      *(bf16x8*)(&Bs[dst + i * 2048]) = cvt8(rb[i][0], rb[i][1]);
    }
    __syncthreads();
    if (kt + 1 < ksteps) LOADK(kt + 1);

    bf16x8 afr[4][2], bfr[4][2];
#pragma unroll
    for (int kk = 0; kk < 2; ++kk) {
#pragma unroll
      for (int t2 = 0; t2 < 4; ++t2) {
        afr[t2][kk] = *(const bf16x8*)(&As[a_base[kk] + t2 * 1024]);
        bfr[t2][kk] = *(const bf16x8*)(&Bs[b_base[kk] + t2 * 1024]);
      }
    }
#pragma unroll
    for (int kk = 0; kk < 2; ++kk) {
#pragma unroll
      for (int mt = 0; mt < 4; ++mt) {
#pragma unroll
        for (int nt = 0; nt < 4; ++nt) {
          acc[mt][nt] = __builtin_amdgcn_mfma_f32_16x16x32_bf16(
              afr[mt][kk], bfr[nt][kk], acc[mt][nt], 0, 0, 0);
        }
      }
    }
    __syncthreads();
  }
#undef LOADK

  float bi[4], sc[4];
#pragma unroll
  for (int nt = 0; nt < 4; ++nt) {
    int n = n0 + wave_n + nt * 16 + lo;
    bi[nt] = bias ? bias[n] : 0.f;
    sc[nt] = scale ? scale[n] : 1.f;
  }
#pragma unroll
  for (int mt = 0; mt < 4; ++mt) {
#pragma unroll
    for (int r = 0; r < 4; ++r) {
      size_t m = (size_t)(m0 + wave_m + mt * 16 + hi * 4 + r);
      unsigned short* rowp = Cb + m * (size_t)N + (n0 + wave_n + lo);
#pragma unroll
      for (int nt = 0; nt < 4; ++nt) {
        float v = fmaxf(acc[mt][nt][r] + bi[nt], 0.f) * sc[nt];
        rowp[nt * 16] = f2bf(v);
      }
    }
  }
}

// ---------------------------------------------------------------------------
// 256x256-tile, BK=64, 8-wave, 8-phase main GEMM (verified round-2 structure).
// C = A@B^T + bconst[0], fp32 out via NON-TEMPORAL stores (C bypasses L2/L3 so
// A (4MB) stays L2-resident and B (32MB) stays L3-resident across re-reads).
__global__ __launch_bounds__(512, 2)
void gemm256_nt(const unsigned short* __restrict__ A,
                const unsigned short* __restrict__ B,
                float* __restrict__ Cf,
                const float* __restrict__ bconst,
                int M, int N, int K) {
  __shared__ unsigned short As[2][256 * 64];
  __shared__ unsigned short Bs[2][256 * 64];

  int nby = N >> 8;
  int nwg = gridDim.x;
  int wg = blockIdx.x;
  if ((nwg & 7) == 0) {
    int cpx = nwg >> 3;
    wg = (wg & 7) * cpx + (wg >> 3);
  }
  int bm = wg / nby, bn = wg % nby;
  int m0 = bm << 8, n0 = bn << 8;

  int tid = threadIdx.x;
  int lane = tid & 63;
  int wid = tid >> 6;
  int wm = wid >> 2, wn = wid & 3;
  int lo = lane & 15, hi = lane >> 4;

  int srow = tid >> 3;
  int schunk = (tid & 7) ^ (srow & 7);
  const unsigned short* Asrc = A + (size_t)(m0 + srow) * K + schunk * 8;
  const unsigned short* Bsrc = B + (size_t)(n0 + srow) * K + schunk * 8;
  int ldst = tid * 8;

  int soff[2];
  soff[0] = (hi ^ (lo & 7)) * 8;
  soff[1] = ((4 + hi) ^ (lo & 7)) * 8;
  int sA_row = (wm * 128 + lo) * 64;
  int sB_row = (wn * 64 + lo) * 64;

  f32x4 acc[8][4] = {};
  bf16x8 afr[4][2], bfr[2][2];

#define STAGE(SRC, LDSB, KT)                                                    \
  {                                                                             \
    _Pragma("unroll") for (int i_ = 0; i_ < 4; ++i_) {                          \
      __builtin_amdgcn_global_load_lds(                                         \
          (const __attribute__((address_space(1))) void*)(                      \
              (SRC) + (size_t)(KT) * 64 + (size_t)(i_ * 64) * K),               \
          (__attribute__((address_space(3))) void*)((LDSB) + i_ * 4096 + ldst), \
          16, 0, 0);                                                            \
    }                                                                           \
  }

#define PHASE(BUF, MH, NH, READA, STAGE_STMT, VM_STMT)                          \
  {                                                                             \
    STAGE_STMT;                                                                 \
    if (READA) {                                                                \
      _Pragma("unroll") for (int i_ = 0; i_ < 4; ++i_)                          \
        _Pragma("unroll") for (int kk_ = 0; kk_ < 2; ++kk_)                     \
          afr[i_][kk_] = *(const bf16x8*)(                                      \
              &As[BUF][sA_row + ((MH) * 4 + i_) * 1024 + soff[kk_]]);           \
    }                                                                           \
    _Pragma("unroll") for (int j_ = 0; j_ < 2; ++j_)                            \
      _Pragma("unroll") for (int kk_ = 0; kk_ < 2; ++kk_)                       \
        bfr[j_][kk_] = *(const bf16x8*)(                                        \
            &Bs[BUF][sB_row + ((NH) * 2 + j_) * 1024 + soff[kk_]]);             \
    __builtin_amdgcn_s_barrier();                                               \
    asm volatile("s_waitcnt lgkmcnt(0)" ::: "memory");                          \
    __builtin_amdgcn_sched_barrier(0);                                          \
    __builtin_amdgcn_s_setprio(1);                                              \
    _Pragma("unroll") for (int i_ = 0; i_ < 4; ++i_)                            \
      _Pragma("unroll") for (int j_ = 0; j_ < 2; ++j_)                          \
        _Pragma("unroll") for (int kk_ = 0; kk_ < 2; ++kk_)                     \
          acc[(MH) * 4 + i_][(NH) * 2 + j_] =                                   \
              __builtin_amdgcn_mfma_f32_16x16x32_bf16(                          \
                  afr[i_][kk_], bfr[j_][kk_],                                   \
                  acc[(MH) * 4 + i_][(NH) * 2 + j_], 0, 0, 0);                  \
    __builtin_amdgcn_s_setprio(0);                                              \
    VM_STMT;                                                                    \
    __builtin_amdgcn_s_barrier();                                               \
  }

  STAGE(Asrc, &As[0][0], 0);
  STAGE(Bsrc, &Bs[0][0], 0);
  asm volatile("s_waitcnt vmcnt(0)" ::: "memory");
  __builtin_amdgcn_s_barrier();

  int KS = K >> 6;
  for (int j = 0; j < KS; j += 2) {
    bool more = (j + 2) < KS;
    PHASE(0, 0, 0, true,  { STAGE(Bsrc, &Bs[1][0], j + 1); }, {});
    PHASE(0, 0, 1, false, { STAGE(Asrc, &As[1][0], j + 1); }, {});
    PHASE(0, 1, 0, true,  {}, {});
    PHASE(0, 1, 1, false, {},
          { asm volatile("s_waitcnt vmcnt(0)" ::: "memory"); });
    PHASE(1, 0, 0, true,  { if (more) STAGE(Bsrc, &Bs[0][0], j + 2); }, {});
    PHASE(1, 0, 1, false, { if (more) STAGE(Asrc, &As[0][0], j + 2); }, {});
    PHASE(1, 1, 0, true,  {}, {});
    PHASE(1, 1, 1, false, {},
          { asm volatile("s_waitcnt vmcnt(0)" ::: "memory"); });
  }
#undef PHASE
#undef STAGE

  // epilogue: fp32 NON-TEMPORAL stores (bypass caches; keep A/B resident)
  float badd = bconst[0];
#pragma unroll
  for (int mt = 0; mt < 8; ++mt) {
#pragma unroll
    for (int r = 0; r < 4; ++r) {
      size_t m = (size_t)(m0 + wm * 128 + mt * 16 + hi * 4 + r);
      float* rowp = Cf + m * (size_t)N + (n0 + wn * 64 + lo);
#pragma unroll
      for (int nt = 0; nt < 4; ++nt) {
        __builtin_nontemporal_store(acc[mt][nt][r] + badd, &rowp[nt * 16]);
      }
    }
  }
}

extern "C" void kernel_launch(void* const* d_in, const int* in_sizes, int n_in,
                              void* d_out, int out_size, void* d_ws, size_t ws_size,
                              hipStream_t stream) {
  const float* h  = (const float*)d_in[0];  // [4096,1024]
  const float* l  = (const float*)d_in[1];  // [32000,512]
  const float* Wh = (const float*)d_in[2];  // [512,1024]
  const float* bh = (const float*)d_in[3];  // [512]
  const float* Wl = (const float*)d_in[4];  // [512,512]
  const float* bl = (const float*)d_in[5];  // [512]
  const float* w  = (const float*)d_in[6];  // [512]
  const float* b  = (const float*)d_in[7];  // [1]
  float* out = (float*)d_out;               // [4096,32000]

  char* ws = (char*)d_ws;
  unsigned short* hawbf = (unsigned short*)(ws + 0);        //  4,194,304 B
  unsigned short* labf  = (unsigned short*)(ws + 4194304);  // 32,768,000 B

  // GEMM1: hawbf = relu(h @ Wh^T + bh) * w   [4096,512], K=1024 (fp32 in)
  gemm128_f32in<<<dim3(32 * 4), dim3(256), 0, stream>>>(
      h, Wh, hawbf, bh, w, 4096, 512, 1024);
  // GEMM2: labf = relu(l @ Wl^T + bl)        [32000,512], K=512 (fp32 in)
  gemm128_f32in<<<dim3(250 * 4), dim3(256), 0, stream>>>(
      l, Wl, labf, bl, nullptr, 32000, 512, 512);
  // main: out = hawbf @ labf^T + b  [4096,32000], K=512 — 8-phase + nt-stores
  gemm256_nt<<<dim3(16 * 125), dim3(512), 0, stream>>>(
      hawbf, labf, out, b, 4096, 32000, 512);
}

// Round 6
// 285.834 us; speedup vs baseline: 1.3636x; 1.0210x over previous
//
#include <hip/hip_runtime.h>
#include <hip/hip_bf16.h>

typedef __attribute__((ext_vector_type(8))) short bf16x8;
typedef __attribute__((ext_vector_type(4))) float f32x4;
typedef __attribute__((ext_vector_type(8))) unsigned short u16x8;

__device__ __forceinline__ unsigned short f2bf(float f) {
  union { float f; unsigned u; } v; v.f = f;
  unsigned r = v.u + 0x7FFFu + ((v.u >> 16) & 1u);
  return (unsigned short)(r >> 16);
}

__device__ __forceinline__ bf16x8 cvt8(f32x4 a, f32x4 b) {
  u16x8 o;
  o[0] = f2bf(a[0]); o[1] = f2bf(a[1]); o[2] = f2bf(a[2]); o[3] = f2bf(a[3]);
  o[4] = f2bf(b[0]); o[5] = f2bf(b[1]); o[6] = f2bf(b[2]); o[7] = f2bf(b[3]);
  union { u16x8 u; bf16x8 s; } c; c.u = o;
  return c.s;
}

// ---------------------------------------------------------------------------
// 128x128-tile NT GEMM with FUSED fp32->bf16 input conversion (proven r3-r5).
__global__ __launch_bounds__(256, 2)
void gemm128_f32in(const float* __restrict__ A, const float* __restrict__ B,
                   unsigned short* __restrict__ Cb,
                   const float* __restrict__ bias, const float* __restrict__ scale,
                   int M, int N, int K) {
  __shared__ unsigned short As[128 * 64];
  __shared__ unsigned short Bs[128 * 64];

  int nby = N >> 7;
  int nwg = gridDim.x;
  int wg = blockIdx.x;
  if ((nwg & 7) == 0) {
    int cpx = nwg >> 3;
    wg = (wg & 7) * cpx + (wg >> 3);
  }
  int bm = wg / nby, bn = wg % nby;
  int m0 = bm << 7, n0 = bn << 7;

  int tid = threadIdx.x;
  int w = tid >> 6, lane = tid & 63;
  int wave_m = (w >> 1) << 6;
  int wave_n = (w & 1) << 6;

  int srow = tid >> 3, c8 = tid & 7;
  int slot = c8 ^ (srow & 7);
  const float* Ag = A + (size_t)(m0 + srow) * K + c8 * 8;
  const float* Bg = B + (size_t)(n0 + srow) * K + c8 * 8;
  int dst = srow * 64 + slot * 8;

  int hi = lane >> 4, lo = lane & 15, e7 = lane & 7;
  int a_base[2], b_base[2];
#pragma unroll
  for (int kk = 0; kk < 2; ++kk) {
    int sl = ((kk << 2) + hi) ^ e7;
    a_base[kk] = (wave_m + lo) * 64 + sl * 8;
    b_base[kk] = (wave_n + lo) * 64 + sl * 8;
  }

  f32x4 acc[4][4] = {};
  f32x4 ra[4][2], rb[4][2];

#define LOADK(KT)                                                         \
  {                                                                       \
    _Pragma("unroll") for (int i_ = 0; i_ < 4; ++i_) {                    \
      const float* pa = Ag + (size_t)(KT) * 64 + (size_t)(i_ * 32) * K;   \
      const float* pb = Bg + (size_t)(KT) * 64 + (size_t)(i_ * 32) * K;   \
      ra[i_][0] = *(const f32x4*)pa; ra[i_][1] = *(const f32x4*)(pa + 4); \
      rb[i_][0] = *(const f32x4*)pb; rb[i_][1] = *(const f32x4*)(pb + 4); \
    }                                                                     \
  }

  LOADK(0);
  int ksteps = K >> 6;
  for (int kt = 0; kt < ksteps; ++kt) {
#pragma unroll
    for (int i = 0; i < 4; ++i) {
      *(bf16x8*)(&As[dst + i * 2048]) = cvt8(ra[i][0], ra[i][1]);
      *(bf16x8*)(&Bs[dst + i * 2048]) = cvt8(rb[i][0], rb[i][1]);
    }
    __syncthreads();
    if (kt + 1 < ksteps) LOADK(kt + 1);

    bf16x8 afr[4][2], bfr[4][2];
#pragma unroll
    for (int kk = 0; kk < 2; ++kk) {
#pragma unroll
      for (int t2 = 0; t2 < 4; ++t2) {
        afr[t2][kk] = *(const bf16x8*)(&As[a_base[kk] + t2 * 1024]);
        bfr[t2][kk] = *(const bf16x8*)(&Bs[b_base[kk] + t2 * 1024]);
      }
    }
#pragma unroll
    for (int kk = 0; kk < 2; ++kk) {
#pragma unroll
      for (int mt = 0; mt < 4; ++mt) {
#pragma unroll
        for (int nt = 0; nt < 4; ++nt) {
          acc[mt][nt] = __builtin_amdgcn_mfma_f32_16x16x32_bf16(
              afr[mt][kk], bfr[nt][kk], acc[mt][nt], 0, 0, 0);
        }
      }
    }
    __syncthreads();
  }
#undef LOADK

  float bi[4], sc[4];
#pragma unroll
  for (int nt = 0; nt < 4; ++nt) {
    int n = n0 + wave_n + nt * 16 + lo;
    bi[nt] = bias ? bias[n] : 0.f;
    sc[nt] = scale ? scale[n] : 1.f;
  }
#pragma unroll
  for (int mt = 0; mt < 4; ++mt) {
#pragma unroll
    for (int r = 0; r < 4; ++r) {
      size_t m = (size_t)(m0 + wave_m + mt * 16 + hi * 4 + r);
      unsigned short* rowp = Cb + m * (size_t)N + (n0 + wave_n + lo);
#pragma unroll
      for (int nt = 0; nt < 4; ++nt) {
        float v = fmaxf(acc[mt][nt][r] + bi[nt], 0.f) * sc[nt];
        rowp[nt * 16] = f2bf(v);
      }
    }
  }
}

// ---------------------------------------------------------------------------
// MAIN GEMM: C[4096][32000] = A[4096][512] @ B[32000][512]^T + b.
// BM=128, BN=256, BK=64, single-buffered LDS (48 KiB) -> 2 blocks/CU.
// m97-proven 2-barrier K-loop; latency hidden by the co-resident block's waves
// (cross-block overlap, m114), including the epilogue write burst.
// Block order: bid&7 = XCD chunk; within chunk (c = bid>>3): bm_local = c&3,
// bn = c>>2 -> each XCD keeps 4 A-tiles (512 KB) L2-resident and the 4 blocks
// sharing a B-tile run concurrently (one L2 fetch; B swept once per XCD).
__global__ __launch_bounds__(512, 4)
void gemm_main(const unsigned short* __restrict__ A,
               const unsigned short* __restrict__ B,
               float* __restrict__ Cf,
               const float* __restrict__ bconst) {
  constexpr int K = 512;
  constexpr int N = 32000;
  __shared__ unsigned short As[128 * 64];   // 16 KiB
  __shared__ unsigned short Bs[256 * 64];   // 32 KiB

  int bid = blockIdx.x;           // 4000 blocks = 8 XCD chunks x (125 bn x 4 bm)
  int chunk = bid & 7;
  int c = bid >> 3;               // 0..499
  int bm = chunk * 4 + (c & 3);   // 0..31
  int bn = c >> 2;                // 0..124
  size_t m0 = (size_t)bm * 128, n0 = (size_t)bn * 256;

  int tid = threadIdx.x;
  int lane = tid & 63;
  int wid = tid >> 6;
  int wm = wid >> 2, wn = wid & 3;          // 2M x 4N waves, 64x64 each
  int lo = lane & 15, hi = lane >> 4;

  // staging: pre-swizzled global source, linear LDS dest (16B/lane)
  int srow = tid >> 3;                      // 0..63
  int kc = (tid & 7) ^ (srow & 7);
  const unsigned short* Asrc = A + (m0 + srow) * K + kc * 8;
  const unsigned short* Bsrc = B + (n0 + srow) * K + kc * 8;
  int ldst = tid * 8;

  int soff[2];
  soff[0] = (hi ^ (lo & 7)) * 8;
  soff[1] = ((4 + hi) ^ (lo & 7)) * 8;

  f32x4 acc[4][4] = {};

  for (int kt = 0; kt < K / 64; ++kt) {
    const unsigned short* Ak = Asrc + kt * 64;
    const unsigned short* Bk = Bsrc + kt * 64;
#pragma unroll
    for (int i = 0; i < 2; ++i) {
      __builtin_amdgcn_global_load_lds(
          (const __attribute__((address_space(1))) void*)(Ak + (size_t)(i * 64) * K),
          (__attribute__((address_space(3))) void*)(&As[0] + i * 4096 + ldst),
          16, 0, 0);
    }
#pragma unroll
    for (int i = 0; i < 4; ++i) {
      __builtin_amdgcn_global_load_lds(
          (const __attribute__((address_space(1))) void*)(Bk + (size_t)(i * 64) * K),
          (__attribute__((address_space(3))) void*)(&Bs[0] + i * 4096 + ldst),
          16, 0, 0);
    }
    __syncthreads();  // drains vmcnt(0): staged data visible

#pragma unroll
    for (int kk = 0; kk < 2; ++kk) {
      bf16x8 afr[4], bfr[4];
#pragma unroll
      for (int mt = 0; mt < 4; ++mt)
        afr[mt] = *(const bf16x8*)(&As[(wm * 64 + mt * 16 + lo) * 64 + soff[kk]]);
#pragma unroll
      for (int nt = 0; nt < 4; ++nt)
        bfr[nt] = *(const bf16x8*)(&Bs[(wn * 64 + nt * 16 + lo) * 64 + soff[kk]]);
#pragma unroll
      for (int mt = 0; mt < 4; ++mt)
#pragma unroll
        for (int nt = 0; nt < 4; ++nt)
          acc[mt][nt] = __builtin_amdgcn_mfma_f32_16x16x32_bf16(
              afr[mt], bfr[nt], acc[mt][nt], 0, 0, 0);
    }
    __syncthreads();  // reads done before next-iter staging
  }

  // epilogue: fp32 stores (normal; co-resident block's MFMA covers the burst)
  float badd = bconst[0];
#pragma unroll
  for (int mt = 0; mt < 4; ++mt) {
#pragma unroll
    for (int r = 0; r < 4; ++r) {
      size_t m = m0 + wm * 64 + mt * 16 + hi * 4 + r;
      float* rowp = Cf + m * (size_t)N + (n0 + wn * 64 + lo);
#pragma unroll
      for (int nt = 0; nt < 4; ++nt) {
        rowp[nt * 16] = acc[mt][nt][r] + badd;
      }
    }
  }
}

extern "C" void kernel_launch(void* const* d_in, const int* in_sizes, int n_in,
                              void* d_out, int out_size, void* d_ws, size_t ws_size,
                              hipStream_t stream) {
  const float* h  = (const float*)d_in[0];  // [4096,1024]
  const float* l  = (const float*)d_in[1];  // [32000,512]
  const float* Wh = (const float*)d_in[2];  // [512,1024]
  const float* bh = (const float*)d_in[3];  // [512]
  const float* Wl = (const float*)d_in[4];  // [512,512]
  const float* bl = (const float*)d_in[5];  // [512]
  const float* w  = (const float*)d_in[6];  // [512]
  const float* b  = (const float*)d_in[7];  // [1]
  float* out = (float*)d_out;               // [4096,32000]

  char* ws = (char*)d_ws;
  unsigned short* hawbf = (unsigned short*)(ws + 0);        //  4,194,304 B
  unsigned short* labf  = (unsigned short*)(ws + 4194304);  // 32,768,000 B

  // GEMM1: hawbf = relu(h @ Wh^T + bh) * w   [4096,512], K=1024 (fp32 in)
  gemm128_f32in<<<dim3(32 * 4), dim3(256), 0, stream>>>(
      h, Wh, hawbf, bh, w, 4096, 512, 1024);
  // GEMM2: labf = relu(l @ Wl^T + bl)        [32000,512], K=512 (fp32 in)
  gemm128_f32in<<<dim3(250 * 4), dim3(256), 0, stream>>>(
      l, Wl, labf, bl, nullptr, 32000, 512, 512);
  // main: out = hawbf @ labf^T + b  [4096,32000] — 2 blocks/CU, XCD-blocked
  gemm_main<<<dim3(4000), dim3(512), 0, stream>>>(hawbf, labf, out, b);
}